// Round 15
// baseline (92.126 us; speedup 1.0000x reference)
//
#include <hip/hip_runtime.h>
#include <hip/hip_bf16.h>

// n=M=10000 nodes, a=K=512, b=N=256, E=320000 edges.  M must be <= MCAP.

#define NB   64    // edge-partition blocks for hist/fill
#define MCAP 10240
#define DYN_LDS 40960

typedef __attribute__((ext_vector_type(8))) short bf16x8;
typedef __attribute__((ext_vector_type(4))) float f32x4;

__device__ inline ushort f2bf(float f) {
    uint b = __float_as_uint(f);
    return (ushort)((b + 0x7FFFu + ((b >> 16) & 1u)) >> 16);  // RNE
}

// ---- fp8 e4m3 (OCP on gfx950) ----
#if __has_builtin(__builtin_amdgcn_cvt_f32_fp8) && __has_builtin(__builtin_amdgcn_cvt_pk_fp8_f32)
#define HW_FP8 1
#endif

__device__ inline uchar f2q(float v) {
#ifdef HW_FP8
    uint r = __builtin_amdgcn_cvt_pk_fp8_f32(v, v, 0u, false);
    return (uchar)(r & 0xFFu);
#else
    if (!(v == v)) return 0x7F;
    uchar s = (v < 0.f) ? 0x80 : 0;
    float a = fabsf(v);
    if (a >= 448.f) return s | 0x7E;
    if (a < 0.015625f) {
        int q = (int)(a * 512.f + 0.5f);
        return s | (uchar)q;
    }
    uint b = __float_as_uint(a);
    uint exp = (b >> 23) & 0xFF;
    uint man = b & 0x7FFFFF;
    uint rman = man + 0x7FFFF + ((man >> 20) & 1);
    if (rman >= 0x800000) { rman = 0; exp++; } else rman &= 0x700000;
    int e8 = (int)exp - 120;
    if (e8 >= 16 || (e8 == 15 && (rman >> 20) == 7)) return s | 0x7E;
    return s | (uchar)((e8 << 3) | (rman >> 20));
#endif
}

template <int SEL>
__device__ inline float q2f(uint packed) {
#ifdef HW_FP8
    return __builtin_amdgcn_cvt_f32_fp8(packed, SEL);
#else
    uchar q = (uchar)(packed >> (SEL * 8));
    uint s = (q >> 7) & 1, e = (q >> 3) & 0xF, m = q & 7;
    float v = (e == 0) ? (float)m * 0.001953125f
                       : __uint_as_float(((e - 7 + 127) << 23) | (m << 20));
    return s ? -v : v;
#endif
}

// ---------------------------------------------------------------------------
// 64x64 MFMA tile.  LDS double-buffered (one barrier per K-iter) + 2-deep
// register prefetch (verified R14).
__device__ void mm_tile64(int tile, char* smem,
                          const ushort* __restrict__ Hb,
                          const ushort* __restrict__ Wt,
                          float* __restrict__ outf,
                          uchar* __restrict__ HWq, int M, int N, int K) {
    ushort (*As0)[40] = (ushort (*)[40])(smem);
    ushort (*Bs0)[40] = (ushort (*)[40])(smem + 5120);
    ushort (*As1)[40] = (ushort (*)[40])(smem + 10240);
    ushort (*Bs1)[40] = (ushort (*)[40])(smem + 15360);
    int mblk = (M + 63) >> 6;
    int m0 = (tile % mblk) * 64, n0 = (tile / mblk) * 64;
    int tid = threadIdx.x;
    int wid = tid >> 6, lane = tid & 63;
    int frow = lane & 15, fg = (lane >> 4) * 8;
    int row = tid >> 2, kc = (tid & 3) * 8;
    int gr = m0 + row;
    bool rowok = gr < M;
    const ushort* pa = Hb + (size_t)gr * K + kc;
    const ushort* pb = Wt + (size_t)(n0 + row) * K + kc;
    f32x4 acc[4] = {};
    int4 ra0 = make_int4(0, 0, 0, 0), ra1 = make_int4(0, 0, 0, 0), rb0, rb1;
    if (rowok) ra0 = *(const int4*)pa;
    rb0 = *(const int4*)pb;
    if (rowok) ra1 = *(const int4*)(pa + 32);
    rb1 = *(const int4*)(pb + 32);
    int iters = K / 32;
    for (int it = 0; it < iters; it += 2) {
        *(int4*)&As0[row][kc] = ra0;
        *(int4*)&Bs0[row][kc] = rb0;
        if (it + 2 < iters) {
            int k0 = (it + 2) * 32;
            ra0 = make_int4(0, 0, 0, 0);
            if (rowok) ra0 = *(const int4*)(pa + k0);
            rb0 = *(const int4*)(pb + k0);
        }
        __syncthreads();
        {
            bf16x8 av  = *(const bf16x8*)&As0[wid * 16 + frow][fg];
            bf16x8 bv0 = *(const bf16x8*)&Bs0[ 0 + frow][fg];
            bf16x8 bv1 = *(const bf16x8*)&Bs0[16 + frow][fg];
            bf16x8 bv2 = *(const bf16x8*)&Bs0[32 + frow][fg];
            bf16x8 bv3 = *(const bf16x8*)&Bs0[48 + frow][fg];
            acc[0] = __builtin_amdgcn_mfma_f32_16x16x32_bf16(av, bv0, acc[0], 0, 0, 0);
            acc[1] = __builtin_amdgcn_mfma_f32_16x16x32_bf16(av, bv1, acc[1], 0, 0, 0);
            acc[2] = __builtin_amdgcn_mfma_f32_16x16x32_bf16(av, bv2, acc[2], 0, 0, 0);
            acc[3] = __builtin_amdgcn_mfma_f32_16x16x32_bf16(av, bv3, acc[3], 0, 0, 0);
        }
        *(int4*)&As1[row][kc] = ra1;
        *(int4*)&Bs1[row][kc] = rb1;
        if (it + 3 < iters) {
            int k0 = (it + 3) * 32;
            ra1 = make_int4(0, 0, 0, 0);
            if (rowok) ra1 = *(const int4*)(pa + k0);
            rb1 = *(const int4*)(pb + k0);
        }
        __syncthreads();
        {
            bf16x8 av  = *(const bf16x8*)&As1[wid * 16 + frow][fg];
            bf16x8 bv0 = *(const bf16x8*)&Bs1[ 0 + frow][fg];
            bf16x8 bv1 = *(const bf16x8*)&Bs1[16 + frow][fg];
            bf16x8 bv2 = *(const bf16x8*)&Bs1[32 + frow][fg];
            bf16x8 bv3 = *(const bf16x8*)&Bs1[48 + frow][fg];
            acc[0] = __builtin_amdgcn_mfma_f32_16x16x32_bf16(av, bv0, acc[0], 0, 0, 0);
            acc[1] = __builtin_amdgcn_mfma_f32_16x16x32_bf16(av, bv1, acc[1], 0, 0, 0);
            acc[2] = __builtin_amdgcn_mfma_f32_16x16x32_bf16(av, bv2, acc[2], 0, 0, 0);
            acc[3] = __builtin_amdgcn_mfma_f32_16x16x32_bf16(av, bv3, acc[3], 0, 0, 0);
        }
    }
    // C/D map: col=lane&15, row=(lane>>4)*4+rr  [verified m89/m91]
    int orow = (lane >> 4) * 4, ocol = lane & 15;
    #pragma unroll
    for (int j = 0; j < 4; ++j) {
        #pragma unroll
        for (int rr = 0; rr < 4; ++rr) {
            int grow = m0 + wid * 16 + orow + rr;
            if (grow < M) {
                int gcol = n0 + j * 16 + ocol;
                float vv = acc[j][rr];
                outf[(size_t)grow * N + gcol] = vv;
                HWq[(size_t)grow * N + gcol] = f2q(vv);
            }
        }
    }
}

// ---------------------------------------------------------------------------
// Prelude: q = W @ emb_w (f32-exact routing path); Wt = bf16(W^T); zero ctrs
__global__ __launch_bounds__(256) void k_prep(const float* __restrict__ W,
                                              const float* __restrict__ emb_w,
                                              float* __restrict__ q,
                                              ushort* __restrict__ Wt,
                                              uint* __restrict__ ctr,
                                              int K, int N) {
    int b = blockIdx.x;
    int nq = K / 4;
    if (b < nq) {
        int wave = threadIdx.x >> 6;
        int lane = threadIdx.x & 63;
        int k = b * 4 + wave;
        float4 w4 = *(const float4*)&W[(size_t)k * N + lane * 4];
        float4 e4 = *(const float4*)&emb_w[lane * 4];
        float s = w4.x * e4.x + w4.y * e4.y + w4.z * e4.z + w4.w * e4.w;
        #pragma unroll
        for (int d = 32; d; d >>= 1) s += __shfl_down(s, d);
        if (lane == 0) q[k] = s;
    } else if (b < nq + (K / 32) * (N / 32)) {
        __shared__ float ts[32][33];
        int idx = b - nq;
        int k0 = (idx % (K / 32)) * 32;
        int n0 = (idx / (K / 32)) * 32;
        int x = threadIdx.x & 31, y = threadIdx.x >> 5;
        #pragma unroll
        for (int i = 0; i < 4; ++i) {
            int kk = y + i * 8;
            ts[kk][x] = W[(size_t)(k0 + kk) * N + n0 + x];
        }
        __syncthreads();
        #pragma unroll
        for (int i = 0; i < 4; ++i) {
            int nn = y + i * 8;
            Wt[(size_t)(n0 + nn) * K + k0 + x] = f2bf(ts[x][nn]);
        }
    } else {
        if (threadIdx.x < 8) ctr[threadIdx.x] = 0;
    }
}

// Fused: Hb = bf16(H)  AND  p[i] = (dot(H[i,:], q) + emb_b) * rv  (f32-exact)
__global__ __launch_bounds__(256) void k_hp(const float* __restrict__ H,
                                            const float* __restrict__ q,
                                            const float* __restrict__ emb_b,
                                            const float* __restrict__ rv,
                                            ushort* __restrict__ Hb,
                                            float* __restrict__ p, int M, int K) {
    int wid = threadIdx.x >> 6, lane = threadIdx.x & 63;
    int i = blockIdx.x * 4 + wid;
    if (i >= M) return;
    const float* h = H + (size_t)i * K;
    float s = 0.f;
    for (int o = lane * 8; o < K; o += 512) {
        float4 a = *(const float4*)&h[o];
        float4 b = *(const float4*)&h[o + 4];
        float4 qa = *(const float4*)&q[o];
        float4 qb = *(const float4*)&q[o + 4];
        s += a.x * qa.x + a.y * qa.y + a.z * qa.z + a.w * qa.w
           + b.x * qb.x + b.y * qb.y + b.z * qb.z + b.w * qb.w;
        ushort u[8] = {f2bf(a.x), f2bf(a.y), f2bf(a.z), f2bf(a.w),
                       f2bf(b.x), f2bf(b.y), f2bf(b.z), f2bf(b.w)};
        *(int4*)&Hb[(size_t)i * K + o] = *(int4*)u;
    }
    #pragma unroll
    for (int d = 32; d; d >>= 1) s += __shfl_down(s, d);
    if (lane == 0) p[i] = (s + emb_b[0]) * rv[0];
}

// ---------------------------------------------------------------------------
// Launch A: blocks [0,NB) = LDS histogram + per-edge cond byte;
//           blocks [NB, NB+tiles64) = 64x64 mm tiles.
__global__ __launch_bounds__(256) void k_hist_mm(const int* __restrict__ st,
                                                 const float* __restrict__ p,
                                                 uint* __restrict__ parthist,
                                                 uchar* __restrict__ condb,
                                                 const ushort* __restrict__ Hb,
                                                 const ushort* __restrict__ Wt,
                                                 float* __restrict__ outf,
                                                 uchar* __restrict__ HWq,
                                                 int E, int M, int N, int K) {
    extern __shared__ char smem[];
    int b = blockIdx.x;
    if (b >= NB) { mm_tile64(b - NB, smem, Hb, Wt, outf, HWq, M, N, K); return; }
    uint* h = (uint*)smem;
    for (int i = threadIdx.x; i < M; i += 256) h[i] = 0;
    __syncthreads();
    int epb = (E + NB - 1) / NB;
    int beg = b * epb, end = min(beg + epb, E);
    for (int e = beg + threadIdx.x; e < end; e += 256) {
        int u = st[e], v = st[E + e];
        bool cond = p[u] > p[v];
        condb[e] = cond ? 1 : 0;
        uint inc = cond ? 1u : (1u << 16);
        atomicAdd(&h[u], inc);
        atomicAdd(&h[v], inc);
    }
    __syncthreads();
    for (int i = threadIdx.x; i < M; i += 256)
        parthist[(size_t)b * M + i] = h[i];
}

// Launch B: per-row merge over NB partials (batched 32-wide loads, in-place
// exclusive cross prefix); LAST block (device ticket) does the global scan.
__global__ __launch_bounds__(256) void k_merge_scan(uint* __restrict__ parthist,
                                                    int* __restrict__ crosscnt,
                                                    float* __restrict__ selfmul,
                                                    int* __restrict__ offsets,
                                                    uint* __restrict__ done,
                                                    int M, int nmerge) {
    int b = blockIdx.x;
    int r = b * 256 + threadIdx.x;
    if (r < M) {
        uint crun = 0, srun = 0;
        for (int c = 0; c < NB / 32; ++c) {
            uint vals[32];
            #pragma unroll
            for (int i = 0; i < 32; ++i)
                vals[i] = parthist[(size_t)(c * 32 + i) * M + r];
            #pragma unroll
            for (int i = 0; i < 32; ++i) {
                parthist[(size_t)(c * 32 + i) * M + r] = crun;
                crun += vals[i] & 0xFFFFu;
                srun += vals[i] >> 16;
            }
        }
        crosscnt[r] = (int)crun;
        selfmul[r] = 1.0f + (float)srun;
    }
    __threadfence();
    __shared__ uint ticket;
    if (threadIdx.x == 0) ticket = atomicAdd(done, 1);
    __syncthreads();
    if (ticket == (uint)(nmerge - 1)) {
        __threadfence();
        __shared__ int s[256];
        int t = threadIdx.x;
        int chunk = (M + 255) / 256;
        int cb = t * chunk;
        int ce = min(cb + chunk, M);
        int sum = 0;
        for (int i = cb; i < ce; ++i) sum += crosscnt[i];
        s[t] = sum;
        __syncthreads();
        for (int d = 1; d < 256; d <<= 1) {
            int val = (t >= d) ? s[t - d] : 0;
            __syncthreads();
            s[t] += val;
            __syncthreads();
        }
        int run = (t == 0) ? 0 : s[t - 1];
        for (int i = cb; i < ce; ++i) {
            offsets[i] = run;
            run += crosscnt[i];
        }
        if (t == 255) offsets[M] = run;
    }
}

// Launch C: slot assignment (LDS cursors; cond read from precomputed byte).
__global__ __launch_bounds__(256) void k_fill(const int* __restrict__ st,
                                              const uchar* __restrict__ condb,
                                              const int* __restrict__ offsets,
                                              const uint* __restrict__ blockbase,
                                              int* __restrict__ colidx,
                                              int E, int M) {
    extern __shared__ char smem[];
    int b = blockIdx.x;
    int* cur = (int*)smem;
    for (int i = threadIdx.x; i < M; i += 256)
        cur[i] = offsets[i] + (int)blockbase[(size_t)b * M + i];
    __syncthreads();
    int epb = (E + NB - 1) / NB;
    int beg = b * epb, end = min(beg + epb, E);
    for (int e = beg + threadIdx.x; e < end; e += 256) {
        if (condb[e]) {
            int u = st[e], v = st[E + e];
            int su = atomicAdd(&cur[u], 1);
            colidx[su] = v;
            int sv = atomicAdd(&cur[v], 1);
            colidx[sv] = u;
        }
    }
}

// ---------------------------------------------------------------------------
// out[r,:] = out[r,:](HW f32) * selfmul[r] + bias + sum_j fp8(HWq[colidx[j],:])
// One WAVE per row; unroll-32 message batch (32 outstanding 4B row-reads per
// lane, 8 accumulator quads, all indices compile-time) + 8/1 remainders.
__global__ __launch_bounds__(256) void k_gather(const uchar* __restrict__ HWq,
                                                const float* __restrict__ bias,
                                                const float* __restrict__ selfmul,
                                                const int* __restrict__ offs,
                                                const int* __restrict__ colidx,
                                                float* __restrict__ out, int N, int M) {
    int wid = threadIdx.x >> 6, lane = threadIdx.x & 63;
    int r = blockIdx.x * 4 + wid;
    if (r >= M) return;
    int beg = offs[r], end = offs[r + 1];
    float ac[8][4] = {};
    int j = beg;
    for (; j + 32 <= end; j += 32) {
        int c32 = colidx[j + (lane & 31)];
        uint mv[32];
        #pragma unroll
        for (int i = 0; i < 32; ++i) {
            int c = __shfl(c32, i, 32);
            mv[i] = *(const uint*)&HWq[(size_t)c * N + lane * 4];
        }
        #pragma unroll
        for (int i = 0; i < 32; ++i) {
            ac[i & 7][0] += q2f<0>(mv[i]);
            ac[i & 7][1] += q2f<1>(mv[i]);
            ac[i & 7][2] += q2f<2>(mv[i]);
            ac[i & 7][3] += q2f<3>(mv[i]);
        }
    }
    for (; j + 8 <= end; j += 8) {
        int c8 = colidx[j + (lane & 7)];
        uint mv[8];
        #pragma unroll
        for (int i = 0; i < 8; ++i) {
            int c = __shfl(c8, i, 8);
            mv[i] = *(const uint*)&HWq[(size_t)c * N + lane * 4];
        }
        #pragma unroll
        for (int i = 0; i < 8; ++i) {
            ac[i][0] += q2f<0>(mv[i]);
            ac[i][1] += q2f<1>(mv[i]);
            ac[i][2] += q2f<2>(mv[i]);
            ac[i][3] += q2f<3>(mv[i]);
        }
    }
    for (; j < end; ++j) {
        int c = colidx[j];
        uint m = *(const uint*)&HWq[(size_t)c * N + lane * 4];
        ac[0][0] += q2f<0>(m);
        ac[0][1] += q2f<1>(m);
        ac[0][2] += q2f<2>(m);
        ac[0][3] += q2f<3>(m);
    }
    float s0 = ((ac[0][0] + ac[1][0]) + (ac[2][0] + ac[3][0]))
             + ((ac[4][0] + ac[5][0]) + (ac[6][0] + ac[7][0]));
    float s1 = ((ac[0][1] + ac[1][1]) + (ac[2][1] + ac[3][1]))
             + ((ac[4][1] + ac[5][1]) + (ac[6][1] + ac[7][1]));
    float s2 = ((ac[0][2] + ac[1][2]) + (ac[2][2] + ac[3][2]))
             + ((ac[4][2] + ac[5][2]) + (ac[6][2] + ac[7][2]));
    float s3 = ((ac[0][3] + ac[1][3]) + (ac[2][3] + ac[3][3]))
             + ((ac[4][3] + ac[5][3]) + (ac[6][3] + ac[7][3]));
    float4 mi = *(const float4*)&out[(size_t)r * N + lane * 4];
    float4 bi = *(const float4*)&bias[lane * 4];
    float sm = selfmul[r];
    float4 o;
    o.x = mi.x * sm + bi.x + s0;
    o.y = mi.y * sm + bi.y + s1;
    o.z = mi.z * sm + bi.z + s2;
    o.w = mi.w * sm + bi.w + s3;
    *(float4*)&out[(size_t)r * N + lane * 4] = o;
}

// ---------------------------------------------------------------------------
extern "C" void kernel_launch(void* const* d_in, const int* in_sizes, int n_in,
                              void* d_out, int out_size, void* d_ws, size_t ws_size,
                              hipStream_t stream) {
    const int*   st    = (const int*)d_in[0];
    const float* H     = (const float*)d_in[1];
    const float* W     = (const float*)d_in[2];
    const float* bias  = (const float*)d_in[3];
    const float* emb_w = (const float*)d_in[4];
    const float* emb_b = (const float*)d_in[5];
    const float* rv    = (const float*)d_in[6];
    float* out = (float*)d_out;

    const int E = in_sizes[0] / 2;       // 320000
    const int N = in_sizes[3];           // 256
    const int K = in_sizes[2] / N;       // 512
    const int M = in_sizes[1] / K;       // 10000  (<= MCAP)

    char* ws = (char*)d_ws;
    size_t off = 0;
    auto alloc = [&](size_t bytes) -> char* {
        char* ptr = ws + off;
        off = (off + bytes + 255) & ~(size_t)255;
        return ptr;
    };
    float*  q        = (float*)alloc((size_t)K * 4);
    float*  p        = (float*)alloc((size_t)M * 4);
    uchar*  HWq      = (uchar*)alloc((size_t)M * N);
    ushort* Hb       = (ushort*)alloc((size_t)M * K * 2);
    ushort* Wt       = (ushort*)alloc((size_t)K * N * 2);
    uint*   parthist = (uint*)alloc((size_t)NB * M * 4);
    int*    crosscnt = (int*)alloc((size_t)M * 4);
    float*  selfmul  = (float*)alloc((size_t)M * 4);
    int*    offsets  = (int*)alloc((size_t)(M + 1) * 4);
    int*    colidx   = (int*)alloc((size_t)2 * E * 4);
    uchar*  condb    = (uchar*)alloc((size_t)E);
    uint*   ctr      = (uint*)alloc(256);
    (void)ws_size; (void)n_in; (void)out_size;

    const int tiles64 = ((M + 63) / 64) * (N / 64);     // 628
    const int nmerge  = (M + 255) / 256;                // 40

    k_prep<<<K / 4 + (K / 32) * (N / 32) + 1, 256, 0, stream>>>(W, emb_w, q, Wt, ctr, K, N);
    k_hp<<<(M + 3) / 4, 256, 0, stream>>>(H, q, emb_b, rv, Hb, p, M, K);
    k_hist_mm<<<NB + tiles64, 256, DYN_LDS, stream>>>(st, p, parthist, condb, Hb, Wt, out, HWq, E, M, N, K);
    k_merge_scan<<<nmerge, 256, 0, stream>>>(parthist, crosscnt, selfmul, offsets, &ctr[0], M, nmerge);
    k_fill<<<NB, 256, DYN_LDS, stream>>>(st, condb, offsets, parthist, colidx, E, M);
    k_gather<<<(M + 3) / 4, 256, 0, stream>>>(HWq, bias, selfmul, offsets, colidx, out, N, M);
}

// Round 16
// 91.574 us; speedup vs baseline: 1.0060x; 1.0060x over previous
//
#include <hip/hip_runtime.h>
#include <hip/hip_bf16.h>

// n=M=10000 nodes, a=K=512, b=N=256, E=320000 edges.  M must be <= MCAP.

#define NB   64    // edge-partition blocks for hist/fill
#define MCAP 10240
#define DYN_LDS 40960

typedef __attribute__((ext_vector_type(8))) short bf16x8;
typedef __attribute__((ext_vector_type(4))) float f32x4;

__device__ inline ushort f2bf(float f) {
    uint b = __float_as_uint(f);
    return (ushort)((b + 0x7FFFu + ((b >> 16) & 1u)) >> 16);  // RNE
}

// ---- fp8 e4m3 (OCP on gfx950) ----
#if __has_builtin(__builtin_amdgcn_cvt_f32_fp8) && __has_builtin(__builtin_amdgcn_cvt_pk_fp8_f32)
#define HW_FP8 1
#endif

__device__ inline uchar f2q(float v) {
#ifdef HW_FP8
    uint r = __builtin_amdgcn_cvt_pk_fp8_f32(v, v, 0u, false);
    return (uchar)(r & 0xFFu);
#else
    if (!(v == v)) return 0x7F;
    uchar s = (v < 0.f) ? 0x80 : 0;
    float a = fabsf(v);
    if (a >= 448.f) return s | 0x7E;
    if (a < 0.015625f) {
        int q = (int)(a * 512.f + 0.5f);
        return s | (uchar)q;
    }
    uint b = __float_as_uint(a);
    uint exp = (b >> 23) & 0xFF;
    uint man = b & 0x7FFFFF;
    uint rman = man + 0x7FFFF + ((man >> 20) & 1);
    if (rman >= 0x800000) { rman = 0; exp++; } else rman &= 0x700000;
    int e8 = (int)exp - 120;
    if (e8 >= 16 || (e8 == 15 && (rman >> 20) == 7)) return s | 0x7E;
    return s | (uchar)((e8 << 3) | (rman >> 20));
#endif
}

template <int SEL>
__device__ inline float q2f(uint packed) {
#ifdef HW_FP8
    return __builtin_amdgcn_cvt_f32_fp8(packed, SEL);
#else
    uchar q = (uchar)(packed >> (SEL * 8));
    uint s = (q >> 7) & 1, e = (q >> 3) & 0xF, m = q & 7;
    float v = (e == 0) ? (float)m * 0.001953125f
                       : __uint_as_float(((e - 7 + 127) << 23) | (m << 20));
    return s ? -v : v;
#endif
}

// ---------------------------------------------------------------------------
// 64x128 MFMA tile: A-band (64 rows) re-read halved vs 64x64 (2x instead of
// 4x), 8 MFMAs per wave-iter.  LDS double-buffered (one barrier per K-iter)
// + 2-deep register prefetch.  LDS: 2*(5120+10240) = 30720 B.
__device__ void mm_tile(int tile, char* smem,
                        const ushort* __restrict__ Hb,
                        const ushort* __restrict__ Wt,
                        float* __restrict__ outf,
                        uchar* __restrict__ HWq, int M, int N, int K) {
    ushort (*As0)[40] = (ushort (*)[40])(smem);
    ushort (*Bs0)[40] = (ushort (*)[40])(smem + 5120);
    ushort (*As1)[40] = (ushort (*)[40])(smem + 15360);
    ushort (*Bs1)[40] = (ushort (*)[40])(smem + 20480);
    int mblk = (M + 63) >> 6;                       // 157
    int m0 = (tile % mblk) * 64, n0 = (tile / mblk) * 128;
    int tid = threadIdx.x;
    int wid = tid >> 6, lane = tid & 63;
    int frow = lane & 15, fg = (lane >> 4) * 8;
    int row = tid >> 2, kc = (tid & 3) * 8;         // A: 64 rows x 32 k
    int gr = m0 + row;
    bool rowok = gr < M;
    const ushort* pa  = Hb + (size_t)gr * K + kc;
    const ushort* pbA = Wt + (size_t)(n0 + row) * K + kc;        // B rows 0..63
    const ushort* pbB = Wt + (size_t)(n0 + 64 + row) * K + kc;   // B rows 64..127
    f32x4 acc[8] = {};
    int4 ra0 = make_int4(0, 0, 0, 0), ra1 = make_int4(0, 0, 0, 0);
    int4 rbA0, rbB0, rbA1, rbB1;
    if (rowok) ra0 = *(const int4*)pa;
    rbA0 = *(const int4*)pbA;
    rbB0 = *(const int4*)pbB;
    if (rowok) ra1 = *(const int4*)(pa + 32);
    rbA1 = *(const int4*)(pbA + 32);
    rbB1 = *(const int4*)(pbB + 32);
    int iters = K / 32;                              // 16 (even)
    for (int it = 0; it < iters; it += 2) {
        // ---- phase 0: buffer 0 holds slab `it` ----
        *(int4*)&As0[row][kc]      = ra0;
        *(int4*)&Bs0[row][kc]      = rbA0;
        *(int4*)&Bs0[64 + row][kc] = rbB0;
        if (it + 2 < iters) {
            int k0 = (it + 2) * 32;
            ra0 = make_int4(0, 0, 0, 0);
            if (rowok) ra0 = *(const int4*)(pa + k0);
            rbA0 = *(const int4*)(pbA + k0);
            rbB0 = *(const int4*)(pbB + k0);
        }
        __syncthreads();
        {
            bf16x8 av = *(const bf16x8*)&As0[wid * 16 + frow][fg];
            #pragma unroll
            for (int j = 0; j < 8; ++j) {
                bf16x8 bv = *(const bf16x8*)&Bs0[j * 16 + frow][fg];
                acc[j] = __builtin_amdgcn_mfma_f32_16x16x32_bf16(av, bv, acc[j], 0, 0, 0);
            }
        }
        // ---- phase 1: buffer 1 holds slab `it+1` ----
        *(int4*)&As1[row][kc]      = ra1;
        *(int4*)&Bs1[row][kc]      = rbA1;
        *(int4*)&Bs1[64 + row][kc] = rbB1;
        if (it + 3 < iters) {
            int k0 = (it + 3) * 32;
            ra1 = make_int4(0, 0, 0, 0);
            if (rowok) ra1 = *(const int4*)(pa + k0);
            rbA1 = *(const int4*)(pbA + k0);
            rbB1 = *(const int4*)(pbB + k0);
        }
        __syncthreads();
        {
            bf16x8 av = *(const bf16x8*)&As1[wid * 16 + frow][fg];
            #pragma unroll
            for (int j = 0; j < 8; ++j) {
                bf16x8 bv = *(const bf16x8*)&Bs1[j * 16 + frow][fg];
                acc[j] = __builtin_amdgcn_mfma_f32_16x16x32_bf16(av, bv, acc[j], 0, 0, 0);
            }
        }
    }
    // C/D map: col=lane&15, row=(lane>>4)*4+rr  [verified m89/m91]
    int orow = (lane >> 4) * 4, ocol = lane & 15;
    #pragma unroll
    for (int j = 0; j < 8; ++j) {
        #pragma unroll
        for (int rr = 0; rr < 4; ++rr) {
            int grow = m0 + wid * 16 + orow + rr;
            if (grow < M) {
                int gcol = n0 + j * 16 + ocol;
                float vv = acc[j][rr];
                outf[(size_t)grow * N + gcol] = vv;
                HWq[(size_t)grow * N + gcol] = f2q(vv);
            }
        }
    }
}

// ---------------------------------------------------------------------------
// Prelude: q = W @ emb_w (f32-exact routing path); Wt = bf16(W^T); zero ctrs
__global__ __launch_bounds__(256) void k_prep(const float* __restrict__ W,
                                              const float* __restrict__ emb_w,
                                              float* __restrict__ q,
                                              ushort* __restrict__ Wt,
                                              uint* __restrict__ ctr,
                                              int K, int N) {
    int b = blockIdx.x;
    int nq = K / 4;
    if (b < nq) {
        int wave = threadIdx.x >> 6;
        int lane = threadIdx.x & 63;
        int k = b * 4 + wave;
        float4 w4 = *(const float4*)&W[(size_t)k * N + lane * 4];
        float4 e4 = *(const float4*)&emb_w[lane * 4];
        float s = w4.x * e4.x + w4.y * e4.y + w4.z * e4.z + w4.w * e4.w;
        #pragma unroll
        for (int d = 32; d; d >>= 1) s += __shfl_down(s, d);
        if (lane == 0) q[k] = s;
    } else if (b < nq + (K / 32) * (N / 32)) {
        __shared__ float ts[32][33];
        int idx = b - nq;
        int k0 = (idx % (K / 32)) * 32;
        int n0 = (idx / (K / 32)) * 32;
        int x = threadIdx.x & 31, y = threadIdx.x >> 5;
        #pragma unroll
        for (int i = 0; i < 4; ++i) {
            int kk = y + i * 8;
            ts[kk][x] = W[(size_t)(k0 + kk) * N + n0 + x];
        }
        __syncthreads();
        #pragma unroll
        for (int i = 0; i < 4; ++i) {
            int nn = y + i * 8;
            Wt[(size_t)(n0 + nn) * K + k0 + x] = f2bf(ts[x][nn]);
        }
    } else {
        if (threadIdx.x < 8) ctr[threadIdx.x] = 0;
    }
}

// Fused: Hb = bf16(H)  AND  p[i] = (dot(H[i,:], q) + emb_b) * rv  (f32-exact)
__global__ __launch_bounds__(256) void k_hp(const float* __restrict__ H,
                                            const float* __restrict__ q,
                                            const float* __restrict__ emb_b,
                                            const float* __restrict__ rv,
                                            ushort* __restrict__ Hb,
                                            float* __restrict__ p, int M, int K) {
    int wid = threadIdx.x >> 6, lane = threadIdx.x & 63;
    int i = blockIdx.x * 4 + wid;
    if (i >= M) return;
    const float* h = H + (size_t)i * K;
    float s = 0.f;
    for (int o = lane * 8; o < K; o += 512) {
        float4 a = *(const float4*)&h[o];
        float4 b = *(const float4*)&h[o + 4];
        float4 qa = *(const float4*)&q[o];
        float4 qb = *(const float4*)&q[o + 4];
        s += a.x * qa.x + a.y * qa.y + a.z * qa.z + a.w * qa.w
           + b.x * qb.x + b.y * qb.y + b.z * qb.z + b.w * qb.w;
        ushort u[8] = {f2bf(a.x), f2bf(a.y), f2bf(a.z), f2bf(a.w),
                       f2bf(b.x), f2bf(b.y), f2bf(b.z), f2bf(b.w)};
        *(int4*)&Hb[(size_t)i * K + o] = *(int4*)u;
    }
    #pragma unroll
    for (int d = 32; d; d >>= 1) s += __shfl_down(s, d);
    if (lane == 0) p[i] = (s + emb_b[0]) * rv[0];
}

// ---------------------------------------------------------------------------
// Launch A: blocks [0,NB) = LDS histogram + per-edge cond byte;
//           blocks [NB, NB+tiles) = 64x128 mm tiles.
__global__ __launch_bounds__(256) void k_hist_mm(const int* __restrict__ st,
                                                 const float* __restrict__ p,
                                                 uint* __restrict__ parthist,
                                                 uchar* __restrict__ condb,
                                                 const ushort* __restrict__ Hb,
                                                 const ushort* __restrict__ Wt,
                                                 float* __restrict__ outf,
                                                 uchar* __restrict__ HWq,
                                                 int E, int M, int N, int K) {
    extern __shared__ char smem[];
    int b = blockIdx.x;
    if (b >= NB) { mm_tile(b - NB, smem, Hb, Wt, outf, HWq, M, N, K); return; }
    uint* h = (uint*)smem;
    for (int i = threadIdx.x; i < M; i += 256) h[i] = 0;
    __syncthreads();
    int epb = (E + NB - 1) / NB;
    int beg = b * epb, end = min(beg + epb, E);
    for (int e = beg + threadIdx.x; e < end; e += 256) {
        int u = st[e], v = st[E + e];
        bool cond = p[u] > p[v];
        condb[e] = cond ? 1 : 0;
        uint inc = cond ? 1u : (1u << 16);
        atomicAdd(&h[u], inc);
        atomicAdd(&h[v], inc);
    }
    __syncthreads();
    for (int i = threadIdx.x; i < M; i += 256)
        parthist[(size_t)b * M + i] = h[i];
}

// Launch B: per-row merge over NB partials (batched 32-wide loads, in-place
// exclusive cross prefix); LAST block (device ticket) does the global scan.
__global__ __launch_bounds__(256) void k_merge_scan(uint* __restrict__ parthist,
                                                    int* __restrict__ crosscnt,
                                                    float* __restrict__ selfmul,
                                                    int* __restrict__ offsets,
                                                    uint* __restrict__ done,
                                                    int M, int nmerge) {
    int b = blockIdx.x;
    int r = b * 256 + threadIdx.x;
    if (r < M) {
        uint crun = 0, srun = 0;
        for (int c = 0; c < NB / 32; ++c) {
            uint vals[32];
            #pragma unroll
            for (int i = 0; i < 32; ++i)
                vals[i] = parthist[(size_t)(c * 32 + i) * M + r];
            #pragma unroll
            for (int i = 0; i < 32; ++i) {
                parthist[(size_t)(c * 32 + i) * M + r] = crun;
                crun += vals[i] & 0xFFFFu;
                srun += vals[i] >> 16;
            }
        }
        crosscnt[r] = (int)crun;
        selfmul[r] = 1.0f + (float)srun;
    }
    __threadfence();
    __shared__ uint ticket;
    if (threadIdx.x == 0) ticket = atomicAdd(done, 1);
    __syncthreads();
    if (ticket == (uint)(nmerge - 1)) {
        __threadfence();
        __shared__ int s[256];
        int t = threadIdx.x;
        int chunk = (M + 255) / 256;
        int cb = t * chunk;
        int ce = min(cb + chunk, M);
        int sum = 0;
        for (int i = cb; i < ce; ++i) sum += crosscnt[i];
        s[t] = sum;
        __syncthreads();
        for (int d = 1; d < 256; d <<= 1) {
            int val = (t >= d) ? s[t - d] : 0;
            __syncthreads();
            s[t] += val;
            __syncthreads();
        }
        int run = (t == 0) ? 0 : s[t - 1];
        for (int i = cb; i < ce; ++i) {
            offsets[i] = run;
            run += crosscnt[i];
        }
        if (t == 255) offsets[M] = run;
    }
}

// Launch C: slot assignment (LDS cursors; cond read from precomputed byte).
__global__ __launch_bounds__(256) void k_fill(const int* __restrict__ st,
                                              const uchar* __restrict__ condb,
                                              const int* __restrict__ offsets,
                                              const uint* __restrict__ blockbase,
                                              int* __restrict__ colidx,
                                              int E, int M) {
    extern __shared__ char smem[];
    int b = blockIdx.x;
    int* cur = (int*)smem;
    for (int i = threadIdx.x; i < M; i += 256)
        cur[i] = offsets[i] + (int)blockbase[(size_t)b * M + i];
    __syncthreads();
    int epb = (E + NB - 1) / NB;
    int beg = b * epb, end = min(beg + epb, E);
    for (int e = beg + threadIdx.x; e < end; e += 256) {
        if (condb[e]) {
            int u = st[e], v = st[E + e];
            int su = atomicAdd(&cur[u], 1);
            colidx[su] = v;
            int sv = atomicAdd(&cur[v], 1);
            colidx[sv] = u;
        }
    }
}

// ---------------------------------------------------------------------------
// out[r,:] = out[r,:](HW f32) * selfmul[r] + bias + sum_j fp8(HWq[colidx[j],:])
// One WAVE per row; unroll-16 (4 accumulator quads), coalesced colidx + shfl.
// (R14-verified configuration; unroll-32 regressed in R15.)
__global__ __launch_bounds__(256) void k_gather(const uchar* __restrict__ HWq,
                                                const float* __restrict__ bias,
                                                const float* __restrict__ selfmul,
                                                const int* __restrict__ offs,
                                                const int* __restrict__ colidx,
                                                float* __restrict__ out, int N, int M) {
    int wid = threadIdx.x >> 6, lane = threadIdx.x & 63;
    int r = blockIdx.x * 4 + wid;
    if (r >= M) return;
    int beg = offs[r], end = offs[r + 1];
    float a0 = 0.f, a1 = 0.f, a2 = 0.f, a3 = 0.f;
    float b0 = 0.f, b1 = 0.f, b2 = 0.f, b3 = 0.f;
    float c0 = 0.f, c1 = 0.f, c2 = 0.f, c3 = 0.f;
    float d0 = 0.f, d1 = 0.f, d2 = 0.f, d3 = 0.f;
    int j = beg;
    for (; j + 16 <= end; j += 16) {
        int c16 = colidx[j + (lane & 15)];
        #pragma unroll
        for (int i = 0; i < 16; i += 4) {
            int ca = __shfl(c16, i,     16);
            int cb = __shfl(c16, i + 1, 16);
            int cc = __shfl(c16, i + 2, 16);
            int cd = __shfl(c16, i + 3, 16);
            uint ma = *(const uint*)&HWq[(size_t)ca * N + lane * 4];
            uint mb = *(const uint*)&HWq[(size_t)cb * N + lane * 4];
            uint mc = *(const uint*)&HWq[(size_t)cc * N + lane * 4];
            uint md = *(const uint*)&HWq[(size_t)cd * N + lane * 4];
            a0 += q2f<0>(ma); a1 += q2f<1>(ma); a2 += q2f<2>(ma); a3 += q2f<3>(ma);
            b0 += q2f<0>(mb); b1 += q2f<1>(mb); b2 += q2f<2>(mb); b3 += q2f<3>(mb);
            c0 += q2f<0>(mc); c1 += q2f<1>(mc); c2 += q2f<2>(mc); c3 += q2f<3>(mc);
            d0 += q2f<0>(md); d1 += q2f<1>(md); d2 += q2f<2>(md); d3 += q2f<3>(md);
        }
    }
    for (; j + 8 <= end; j += 8) {
        int c8 = colidx[j + (lane & 7)];
        #pragma unroll
        for (int i = 0; i < 8; i += 2) {
            int ca = __shfl(c8, i, 8);
            int cb = __shfl(c8, i + 1, 8);
            uint ma = *(const uint*)&HWq[(size_t)ca * N + lane * 4];
            uint mb = *(const uint*)&HWq[(size_t)cb * N + lane * 4];
            a0 += q2f<0>(ma); a1 += q2f<1>(ma); a2 += q2f<2>(ma); a3 += q2f<3>(ma);
            b0 += q2f<0>(mb); b1 += q2f<1>(mb); b2 += q2f<2>(mb); b3 += q2f<3>(mb);
        }
    }
    for (; j < end; ++j) {
        int c = colidx[j];
        uint m = *(const uint*)&HWq[(size_t)c * N + lane * 4];
        a0 += q2f<0>(m); a1 += q2f<1>(m); a2 += q2f<2>(m); a3 += q2f<3>(m);
    }
    float4 mi = *(const float4*)&out[(size_t)r * N + lane * 4];
    float4 bi = *(const float4*)&bias[lane * 4];
    float sm = selfmul[r];
    float4 o;
    o.x = mi.x * sm + bi.x + (a0 + b0) + (c0 + d0);
    o.y = mi.y * sm + bi.y + (a1 + b1) + (c1 + d1);
    o.z = mi.z * sm + bi.z + (a2 + b2) + (c2 + d2);
    o.w = mi.w * sm + bi.w + (a3 + b3) + (c3 + d3);
    *(float4*)&out[(size_t)r * N + lane * 4] = o;
}

// ---------------------------------------------------------------------------
extern "C" void kernel_launch(void* const* d_in, const int* in_sizes, int n_in,
                              void* d_out, int out_size, void* d_ws, size_t ws_size,
                              hipStream_t stream) {
    const int*   st    = (const int*)d_in[0];
    const float* H     = (const float*)d_in[1];
    const float* W     = (const float*)d_in[2];
    const float* bias  = (const float*)d_in[3];
    const float* emb_w = (const float*)d_in[4];
    const float* emb_b = (const float*)d_in[5];
    const float* rv    = (const float*)d_in[6];
    float* out = (float*)d_out;

    const int E = in_sizes[0] / 2;       // 320000
    const int N = in_sizes[3];           // 256
    const int K = in_sizes[2] / N;       // 512
    const int M = in_sizes[1] / K;       // 10000  (<= MCAP)

    char* ws = (char*)d_ws;
    size_t off = 0;
    auto alloc = [&](size_t bytes) -> char* {
        char* ptr = ws + off;
        off = (off + bytes + 255) & ~(size_t)255;
        return ptr;
    };
    float*  q        = (float*)alloc((size_t)K * 4);
    float*  p        = (float*)alloc((size_t)M * 4);
    uchar*  HWq      = (uchar*)alloc((size_t)M * N);
    ushort* Hb       = (ushort*)alloc((size_t)M * K * 2);
    ushort* Wt       = (ushort*)alloc((size_t)K * N * 2);
    uint*   parthist = (uint*)alloc((size_t)NB * M * 4);
    int*    crosscnt = (int*)alloc((size_t)M * 4);
    float*  selfmul  = (float*)alloc((size_t)M * 4);
    int*    offsets  = (int*)alloc((size_t)(M + 1) * 4);
    int*    colidx   = (int*)alloc((size_t)2 * E * 4);
    uchar*  condb    = (uchar*)alloc((size_t)E);
    uint*   ctr      = (uint*)alloc(256);
    (void)ws_size; (void)n_in; (void)out_size;

    const int tiles  = ((M + 63) / 64) * (N / 128);     // 157*2 = 314
    const int nmerge = (M + 255) / 256;                 // 40

    k_prep<<<K / 4 + (K / 32) * (N / 32) + 1, 256, 0, stream>>>(W, emb_w, q, Wt, ctr, K, N);
    k_hp<<<(M + 3) / 4, 256, 0, stream>>>(H, q, emb_b, rv, Hb, p, M, K);
    k_hist_mm<<<NB + tiles, 256, DYN_LDS, stream>>>(st, p, parthist, condb, Hb, Wt, out, HWq, E, M, N, K);
    k_merge_scan<<<nmerge, 256, 0, stream>>>(parthist, crosscnt, selfmul, offsets, &ctr[0], M, nmerge);
    k_fill<<<NB, 256, DYN_LDS, stream>>>(st, condb, offsets, parthist, colidx, E, M);
    k_gather<<<(M + 3) / 4, 256, 0, stream>>>(HWq, bias, selfmul, offsets, colidx, out, N, M);
}

// Round 17
// 89.811 us; speedup vs baseline: 1.0258x; 1.0196x over previous
//
#include <hip/hip_runtime.h>
#include <hip/hip_bf16.h>

// n=M=10000 nodes, a=K=512, b=N=256, E=320000 edges.  M must be <= MCAP.
// Best-measured configuration (R14: 90.4 us): 6-launch pipeline, 64x64
// dbuf MFMA tiles co-scheduled with hist, fp8 message gather unroll-16.

#define NB   64    // edge-partition blocks for hist/fill
#define MCAP 10240
#define DYN_LDS 40960

typedef __attribute__((ext_vector_type(8))) short bf16x8;
typedef __attribute__((ext_vector_type(4))) float f32x4;

__device__ inline ushort f2bf(float f) {
    uint b = __float_as_uint(f);
    return (ushort)((b + 0x7FFFu + ((b >> 16) & 1u)) >> 16);  // RNE
}

// ---- fp8 e4m3 (OCP on gfx950) ----
#if __has_builtin(__builtin_amdgcn_cvt_f32_fp8) && __has_builtin(__builtin_amdgcn_cvt_pk_fp8_f32)
#define HW_FP8 1
#endif

__device__ inline uchar f2q(float v) {
#ifdef HW_FP8
    uint r = __builtin_amdgcn_cvt_pk_fp8_f32(v, v, 0u, false);
    return (uchar)(r & 0xFFu);
#else
    if (!(v == v)) return 0x7F;
    uchar s = (v < 0.f) ? 0x80 : 0;
    float a = fabsf(v);
    if (a >= 448.f) return s | 0x7E;
    if (a < 0.015625f) {
        int q = (int)(a * 512.f + 0.5f);
        return s | (uchar)q;
    }
    uint b = __float_as_uint(a);
    uint exp = (b >> 23) & 0xFF;
    uint man = b & 0x7FFFFF;
    uint rman = man + 0x7FFFF + ((man >> 20) & 1);
    if (rman >= 0x800000) { rman = 0; exp++; } else rman &= 0x700000;
    int e8 = (int)exp - 120;
    if (e8 >= 16 || (e8 == 15 && (rman >> 20) == 7)) return s | 0x7E;
    return s | (uchar)((e8 << 3) | (rman >> 20));
#endif
}

template <int SEL>
__device__ inline float q2f(uint packed) {
#ifdef HW_FP8
    return __builtin_amdgcn_cvt_f32_fp8(packed, SEL);
#else
    uchar q = (uchar)(packed >> (SEL * 8));
    uint s = (q >> 7) & 1, e = (q >> 3) & 0xF, m = q & 7;
    float v = (e == 0) ? (float)m * 0.001953125f
                       : __uint_as_float(((e - 7 + 127) << 23) | (m << 20));
    return s ? -v : v;
#endif
}

// ---------------------------------------------------------------------------
// 64x64 MFMA tile.  LDS double-buffered (one barrier per K-iter) + 2-deep
// register prefetch (named regs, static indexing).
__device__ void mm_tile64(int tile, char* smem,
                          const ushort* __restrict__ Hb,
                          const ushort* __restrict__ Wt,
                          float* __restrict__ outf,
                          uchar* __restrict__ HWq, int M, int N, int K) {
    ushort (*As0)[40] = (ushort (*)[40])(smem);
    ushort (*Bs0)[40] = (ushort (*)[40])(smem + 5120);
    ushort (*As1)[40] = (ushort (*)[40])(smem + 10240);
    ushort (*Bs1)[40] = (ushort (*)[40])(smem + 15360);
    int mblk = (M + 63) >> 6;
    int m0 = (tile % mblk) * 64, n0 = (tile / mblk) * 64;
    int tid = threadIdx.x;
    int wid = tid >> 6, lane = tid & 63;
    int frow = lane & 15, fg = (lane >> 4) * 8;
    int row = tid >> 2, kc = (tid & 3) * 8;
    int gr = m0 + row;
    bool rowok = gr < M;
    const ushort* pa = Hb + (size_t)gr * K + kc;
    const ushort* pb = Wt + (size_t)(n0 + row) * K + kc;
    f32x4 acc[4] = {};
    int4 ra0 = make_int4(0, 0, 0, 0), ra1 = make_int4(0, 0, 0, 0), rb0, rb1;
    if (rowok) ra0 = *(const int4*)pa;
    rb0 = *(const int4*)pb;
    if (rowok) ra1 = *(const int4*)(pa + 32);
    rb1 = *(const int4*)(pb + 32);
    int iters = K / 32;
    for (int it = 0; it < iters; it += 2) {
        *(int4*)&As0[row][kc] = ra0;
        *(int4*)&Bs0[row][kc] = rb0;
        if (it + 2 < iters) {
            int k0 = (it + 2) * 32;
            ra0 = make_int4(0, 0, 0, 0);
            if (rowok) ra0 = *(const int4*)(pa + k0);
            rb0 = *(const int4*)(pb + k0);
        }
        __syncthreads();
        {
            bf16x8 av  = *(const bf16x8*)&As0[wid * 16 + frow][fg];
            bf16x8 bv0 = *(const bf16x8*)&Bs0[ 0 + frow][fg];
            bf16x8 bv1 = *(const bf16x8*)&Bs0[16 + frow][fg];
            bf16x8 bv2 = *(const bf16x8*)&Bs0[32 + frow][fg];
            bf16x8 bv3 = *(const bf16x8*)&Bs0[48 + frow][fg];
            acc[0] = __builtin_amdgcn_mfma_f32_16x16x32_bf16(av, bv0, acc[0], 0, 0, 0);
            acc[1] = __builtin_amdgcn_mfma_f32_16x16x32_bf16(av, bv1, acc[1], 0, 0, 0);
            acc[2] = __builtin_amdgcn_mfma_f32_16x16x32_bf16(av, bv2, acc[2], 0, 0, 0);
            acc[3] = __builtin_amdgcn_mfma_f32_16x16x32_bf16(av, bv3, acc[3], 0, 0, 0);
        }
        *(int4*)&As1[row][kc] = ra1;
        *(int4*)&Bs1[row][kc] = rb1;
        if (it + 3 < iters) {
            int k0 = (it + 3) * 32;
            ra1 = make_int4(0, 0, 0, 0);
            if (rowok) ra1 = *(const int4*)(pa + k0);
            rb1 = *(const int4*)(pb + k0);
        }
        __syncthreads();
        {
            bf16x8 av  = *(const bf16x8*)&As1[wid * 16 + frow][fg];
            bf16x8 bv0 = *(const bf16x8*)&Bs1[ 0 + frow][fg];
            bf16x8 bv1 = *(const bf16x8*)&Bs1[16 + frow][fg];
            bf16x8 bv2 = *(const bf16x8*)&Bs1[32 + frow][fg];
            bf16x8 bv3 = *(const bf16x8*)&Bs1[48 + frow][fg];
            acc[0] = __builtin_amdgcn_mfma_f32_16x16x32_bf16(av, bv0, acc[0], 0, 0, 0);
            acc[1] = __builtin_amdgcn_mfma_f32_16x16x32_bf16(av, bv1, acc[1], 0, 0, 0);
            acc[2] = __builtin_amdgcn_mfma_f32_16x16x32_bf16(av, bv2, acc[2], 0, 0, 0);
            acc[3] = __builtin_amdgcn_mfma_f32_16x16x32_bf16(av, bv3, acc[3], 0, 0, 0);
        }
    }
    // C/D map: col=lane&15, row=(lane>>4)*4+rr  [verified m89/m91]
    int orow = (lane >> 4) * 4, ocol = lane & 15;
    #pragma unroll
    for (int j = 0; j < 4; ++j) {
        #pragma unroll
        for (int rr = 0; rr < 4; ++rr) {
            int grow = m0 + wid * 16 + orow + rr;
            if (grow < M) {
                int gcol = n0 + j * 16 + ocol;
                float vv = acc[j][rr];
                outf[(size_t)grow * N + gcol] = vv;
                HWq[(size_t)grow * N + gcol] = f2q(vv);
            }
        }
    }
}

// ---------------------------------------------------------------------------
// Prelude: q = W @ emb_w (f32-exact routing path); Wt = bf16(W^T); zero ctrs
__global__ __launch_bounds__(256) void k_prep(const float* __restrict__ W,
                                              const float* __restrict__ emb_w,
                                              float* __restrict__ q,
                                              ushort* __restrict__ Wt,
                                              uint* __restrict__ ctr,
                                              int K, int N) {
    int b = blockIdx.x;
    int nq = K / 4;
    if (b < nq) {
        int wave = threadIdx.x >> 6;
        int lane = threadIdx.x & 63;
        int k = b * 4 + wave;
        float4 w4 = *(const float4*)&W[(size_t)k * N + lane * 4];
        float4 e4 = *(const float4*)&emb_w[lane * 4];
        float s = w4.x * e4.x + w4.y * e4.y + w4.z * e4.z + w4.w * e4.w;
        #pragma unroll
        for (int d = 32; d; d >>= 1) s += __shfl_down(s, d);
        if (lane == 0) q[k] = s;
    } else if (b < nq + (K / 32) * (N / 32)) {
        __shared__ float ts[32][33];
        int idx = b - nq;
        int k0 = (idx % (K / 32)) * 32;
        int n0 = (idx / (K / 32)) * 32;
        int x = threadIdx.x & 31, y = threadIdx.x >> 5;
        #pragma unroll
        for (int i = 0; i < 4; ++i) {
            int kk = y + i * 8;
            ts[kk][x] = W[(size_t)(k0 + kk) * N + n0 + x];
        }
        __syncthreads();
        #pragma unroll
        for (int i = 0; i < 4; ++i) {
            int nn = y + i * 8;
            Wt[(size_t)(n0 + nn) * K + k0 + x] = f2bf(ts[x][nn]);
        }
    } else {
        if (threadIdx.x < 8) ctr[threadIdx.x] = 0;
    }
}

// Fused: Hb = bf16(H)  AND  p[i] = (dot(H[i,:], q) + emb_b) * rv  (f32-exact)
__global__ __launch_bounds__(256) void k_hp(const float* __restrict__ H,
                                            const float* __restrict__ q,
                                            const float* __restrict__ emb_b,
                                            const float* __restrict__ rv,
                                            ushort* __restrict__ Hb,
                                            float* __restrict__ p, int M, int K) {
    int wid = threadIdx.x >> 6, lane = threadIdx.x & 63;
    int i = blockIdx.x * 4 + wid;
    if (i >= M) return;
    const float* h = H + (size_t)i * K;
    float s = 0.f;
    for (int o = lane * 8; o < K; o += 512) {
        float4 a = *(const float4*)&h[o];
        float4 b = *(const float4*)&h[o + 4];
        float4 qa = *(const float4*)&q[o];
        float4 qb = *(const float4*)&q[o + 4];
        s += a.x * qa.x + a.y * qa.y + a.z * qa.z + a.w * qa.w
           + b.x * qb.x + b.y * qb.y + b.z * qb.z + b.w * qb.w;
        ushort u[8] = {f2bf(a.x), f2bf(a.y), f2bf(a.z), f2bf(a.w),
                       f2bf(b.x), f2bf(b.y), f2bf(b.z), f2bf(b.w)};
        *(int4*)&Hb[(size_t)i * K + o] = *(int4*)u;
    }
    #pragma unroll
    for (int d = 32; d; d >>= 1) s += __shfl_down(s, d);
    if (lane == 0) p[i] = (s + emb_b[0]) * rv[0];
}

// ---------------------------------------------------------------------------
// Launch A: blocks [0,NB) = per-block LDS histogram (cross lo16 / self hi16);
//           blocks [NB, NB+tiles64) = 64x64 mm tiles (one per block).
__global__ __launch_bounds__(256) void k_hist_mm(const int* __restrict__ st,
                                                 const float* __restrict__ p,
                                                 uint* __restrict__ parthist,
                                                 const ushort* __restrict__ Hb,
                                                 const ushort* __restrict__ Wt,
                                                 float* __restrict__ outf,
                                                 uchar* __restrict__ HWq,
                                                 int E, int M, int N, int K) {
    extern __shared__ char smem[];
    int b = blockIdx.x;
    if (b >= NB) { mm_tile64(b - NB, smem, Hb, Wt, outf, HWq, M, N, K); return; }
    uint* h = (uint*)smem;
    for (int i = threadIdx.x; i < M; i += 256) h[i] = 0;
    __syncthreads();
    int epb = (E + NB - 1) / NB;
    int beg = b * epb, end = min(beg + epb, E);
    for (int e = beg + threadIdx.x; e < end; e += 256) {
        int u = st[e], v = st[E + e];
        uint inc = (p[u] > p[v]) ? 1u : (1u << 16);
        atomicAdd(&h[u], inc);
        atomicAdd(&h[v], inc);
    }
    __syncthreads();
    for (int i = threadIdx.x; i < M; i += 256)
        parthist[(size_t)b * M + i] = h[i];
}

// Launch B: per-row merge over NB partials (batched 32-wide loads, in-place
// exclusive cross prefix); LAST block (device ticket) does the global scan.
__global__ __launch_bounds__(256) void k_merge_scan(uint* __restrict__ parthist,
                                                    int* __restrict__ crosscnt,
                                                    float* __restrict__ selfmul,
                                                    int* __restrict__ offsets,
                                                    uint* __restrict__ done,
                                                    int M, int nmerge) {
    int b = blockIdx.x;
    int r = b * 256 + threadIdx.x;
    if (r < M) {
        uint crun = 0, srun = 0;
        for (int c = 0; c < NB / 32; ++c) {
            uint vals[32];
            #pragma unroll
            for (int i = 0; i < 32; ++i)
                vals[i] = parthist[(size_t)(c * 32 + i) * M + r];
            #pragma unroll
            for (int i = 0; i < 32; ++i) {
                parthist[(size_t)(c * 32 + i) * M + r] = crun;
                crun += vals[i] & 0xFFFFu;
                srun += vals[i] >> 16;
            }
        }
        crosscnt[r] = (int)crun;
        selfmul[r] = 1.0f + (float)srun;
    }
    __threadfence();
    __shared__ uint ticket;
    if (threadIdx.x == 0) ticket = atomicAdd(done, 1);
    __syncthreads();
    if (ticket == (uint)(nmerge - 1)) {
        __threadfence();
        __shared__ int s[256];
        int t = threadIdx.x;
        int chunk = (M + 255) / 256;
        int cb = t * chunk;
        int ce = min(cb + chunk, M);
        int sum = 0;
        for (int i = cb; i < ce; ++i) sum += crosscnt[i];
        s[t] = sum;
        __syncthreads();
        for (int d = 1; d < 256; d <<= 1) {
            int val = (t >= d) ? s[t - d] : 0;
            __syncthreads();
            s[t] += val;
            __syncthreads();
        }
        int run = (t == 0) ? 0 : s[t - 1];
        for (int i = cb; i < ce; ++i) {
            offsets[i] = run;
            run += crosscnt[i];
        }
        if (t == 255) offsets[M] = run;
    }
}

// Launch C: slot assignment (LDS cursors; cross edges only).
__global__ __launch_bounds__(256) void k_fill(const int* __restrict__ st,
                                              const float* __restrict__ p,
                                              const int* __restrict__ offsets,
                                              const uint* __restrict__ blockbase,
                                              int* __restrict__ colidx,
                                              int E, int M) {
    extern __shared__ char smem[];
    int b = blockIdx.x;
    int* cur = (int*)smem;
    for (int i = threadIdx.x; i < M; i += 256)
        cur[i] = offsets[i] + (int)blockbase[(size_t)b * M + i];
    __syncthreads();
    int epb = (E + NB - 1) / NB;
    int beg = b * epb, end = min(beg + epb, E);
    for (int e = beg + threadIdx.x; e < end; e += 256) {
        int u = st[e], v = st[E + e];
        if (p[u] > p[v]) {
            int su = atomicAdd(&cur[u], 1);
            colidx[su] = v;
            int sv = atomicAdd(&cur[v], 1);
            colidx[sv] = u;
        }
    }
}

// ---------------------------------------------------------------------------
// out[r,:] = out[r,:](HW f32 from mm) * selfmul[r] + bias + sum_j fp8 msgs
__global__ __launch_bounds__(256) void k_gather(const uchar* __restrict__ HWq,
                                                const float* __restrict__ bias,
                                                const float* __restrict__ selfmul,
                                                const int* __restrict__ offs,
                                                const int* __restrict__ colidx,
                                                float* __restrict__ out, int N, int M) {
    int wid = threadIdx.x >> 6, lane = threadIdx.x & 63;
    int r = blockIdx.x * 4 + wid;
    if (r >= M) return;
    int beg = offs[r], end = offs[r + 1];
    float a0 = 0.f, a1 = 0.f, a2 = 0.f, a3 = 0.f;
    float b0 = 0.f, b1 = 0.f, b2 = 0.f, b3 = 0.f;
    float c0 = 0.f, c1 = 0.f, c2 = 0.f, c3 = 0.f;
    float d0 = 0.f, d1 = 0.f, d2 = 0.f, d3 = 0.f;
    int j = beg;
    for (; j + 16 <= end; j += 16) {
        int c16 = colidx[j + (lane & 15)];
        #pragma unroll
        for (int i = 0; i < 16; i += 4) {
            int ca = __shfl(c16, i,     16);
            int cb = __shfl(c16, i + 1, 16);
            int cc = __shfl(c16, i + 2, 16);
            int cd = __shfl(c16, i + 3, 16);
            uint ma = *(const uint*)&HWq[(size_t)ca * N + lane * 4];
            uint mb = *(const uint*)&HWq[(size_t)cb * N + lane * 4];
            uint mc = *(const uint*)&HWq[(size_t)cc * N + lane * 4];
            uint md = *(const uint*)&HWq[(size_t)cd * N + lane * 4];
            a0 += q2f<0>(ma); a1 += q2f<1>(ma); a2 += q2f<2>(ma); a3 += q2f<3>(ma);
            b0 += q2f<0>(mb); b1 += q2f<1>(mb); b2 += q2f<2>(mb); b3 += q2f<3>(mb);
            c0 += q2f<0>(mc); c1 += q2f<1>(mc); c2 += q2f<2>(mc); c3 += q2f<3>(mc);
            d0 += q2f<0>(md); d1 += q2f<1>(md); d2 += q2f<2>(md); d3 += q2f<3>(md);
        }
    }
    for (; j + 8 <= end; j += 8) {
        int c8 = colidx[j + (lane & 7)];
        #pragma unroll
        for (int i = 0; i < 8; i += 2) {
            int ca = __shfl(c8, i, 8);
            int cb = __shfl(c8, i + 1, 8);
            uint ma = *(const uint*)&HWq[(size_t)ca * N + lane * 4];
            uint mb = *(const uint*)&HWq[(size_t)cb * N + lane * 4];
            a0 += q2f<0>(ma); a1 += q2f<1>(ma); a2 += q2f<2>(ma); a3 += q2f<3>(ma);
            b0 += q2f<0>(mb); b1 += q2f<1>(mb); b2 += q2f<2>(mb); b3 += q2f<3>(mb);
        }
    }
    for (; j < end; ++j) {
        int c = colidx[j];
        uint m = *(const uint*)&HWq[(size_t)c * N + lane * 4];
        a0 += q2f<0>(m); a1 += q2f<1>(m); a2 += q2f<2>(m); a3 += q2f<3>(m);
    }
    float4 mi = *(const float4*)&out[(size_t)r * N + lane * 4];
    float4 bi = *(const float4*)&bias[lane * 4];
    float sm = selfmul[r];
    float4 o;
    o.x = mi.x * sm + bi.x + (a0 + b0) + (c0 + d0);
    o.y = mi.y * sm + bi.y + (a1 + b1) + (c1 + d1);
    o.z = mi.z * sm + bi.z + (a2 + b2) + (c2 + d2);
    o.w = mi.w * sm + bi.w + (a3 + b3) + (c3 + d3);
    *(float4*)&out[(size_t)r * N + lane * 4] = o;
}

// ---------------------------------------------------------------------------
extern "C" void kernel_launch(void* const* d_in, const int* in_sizes, int n_in,
                              void* d_out, int out_size, void* d_ws, size_t ws_size,
                              hipStream_t stream) {
    const int*   st    = (const int*)d_in[0];
    const float* H     = (const float*)d_in[1];
    const float* W     = (const float*)d_in[2];
    const float* bias  = (const float*)d_in[3];
    const float* emb_w = (const float*)d_in[4];
    const float* emb_b = (const float*)d_in[5];
    const float* rv    = (const float*)d_in[6];
    float* out = (float*)d_out;

    const int E = in_sizes[0] / 2;       // 320000
    const int N = in_sizes[3];           // 256
    const int K = in_sizes[2] / N;       // 512
    const int M = in_sizes[1] / K;       // 10000  (<= MCAP)

    char* ws = (char*)d_ws;
    size_t off = 0;
    auto alloc = [&](size_t bytes) -> char* {
        char* ptr = ws + off;
        off = (off + bytes + 255) & ~(size_t)255;
        return ptr;
    };
    float*  q        = (float*)alloc((size_t)K * 4);
    float*  p        = (float*)alloc((size_t)M * 4);
    uchar*  HWq      = (uchar*)alloc((size_t)M * N);
    ushort* Hb       = (ushort*)alloc((size_t)M * K * 2);
    ushort* Wt       = (ushort*)alloc((size_t)K * N * 2);
    uint*   parthist = (uint*)alloc((size_t)NB * M * 4);
    int*    crosscnt = (int*)alloc((size_t)M * 4);
    float*  selfmul  = (float*)alloc((size_t)M * 4);
    int*    offsets  = (int*)alloc((size_t)(M + 1) * 4);
    int*    colidx   = (int*)alloc((size_t)2 * E * 4);
    uint*   ctr      = (uint*)alloc(256);
    (void)ws_size; (void)n_in; (void)out_size;

    const int tiles64 = ((M + 63) / 64) * (N / 64);     // 628
    const int nmerge  = (M + 255) / 256;                // 40

    k_prep<<<K / 4 + (K / 32) * (N / 32) + 1, 256, 0, stream>>>(W, emb_w, q, Wt, ctr, K, N);
    k_hp<<<(M + 3) / 4, 256, 0, stream>>>(H, q, emb_b, rv, Hb, p, M, K);
    k_hist_mm<<<NB + tiles64, 256, DYN_LDS, stream>>>(st, p, parthist, Hb, Wt, out, HWq, E, M, N, K);
    k_merge_scan<<<nmerge, 256, 0, stream>>>(parthist, crosscnt, selfmul, offsets, &ctr[0], M, nmerge);
    k_fill<<<NB, 256, DYN_LDS, stream>>>(st, p, offsets, parthist, colidx, E, M);
    k_gather<<<(M + 3) / 4, 256, 0, stream>>>(HWq, bias, selfmul, offsets, colidx, out, N, M);
}